// Round 5
// baseline (210.650 us; speedup 1.0000x reference)
//
#include <hip/hip_runtime.h>

// VelvetNoise as a pure gather: out[b,n,d] = sgn[b,p,d] * (trunc(23*frac[b,p,d]) == n%24),
// p = n/24. Disjoint scatter windows -> each output element written exactly once.
//
// R5: x8 unroll along k (chunks of +12000 samples = +500 pulses; 12000%24==0 so
// r and the single /24 divide are shared across all 8 chunks). 16 loads issued
// back-to-back (MLP), 8 coalesced float4 stores amortize all index math.
// Exact grid (250, 32) x 192 threads. Plain stores (harness fill proves plain
// stores reach 6.7 TB/s). Traffic floor: 196.6 MB written + ~16 MB read.

#define VN_B  32
#define VN_PS 4000
#define VN_D  16
#define VN_N  96000

typedef float v4f __attribute__((ext_vector_type(4)));

__global__ __launch_bounds__(192) void velvet_gather8(
    const float* __restrict__ in,   // (B, PS, 2*D): [:,:,0:16]=sgn, [:,:,16:32]=frac
    float* __restrict__ out)        // (B, N, D)
{
    const int tid = blockIdx.x * 192 + threadIdx.x;   // [0, 48000) per b
    const int b   = blockIdx.y;

    const int n  = tid >> 2;            // [0, 12000) sample index (k=0)
    const int d0 = (tid & 3) << 2;      // channel group {0,4,8,12}
    const int p  = n / 24;              // magic-mul divide (constant)
    const int r  = n - 24 * p;          // shared by all 8 k-chunks

    const float* base = in + (size_t)b * (VN_PS * 2 * VN_D) + p * (2 * VN_D) + d0;

    // k-chunk input stride: 500 pulses = 16000 floats. Issue all 16 loads first.
    v4f s0 = *(const v4f*)(base);
    v4f f0 = *(const v4f*)(base + VN_D);
    v4f s1 = *(const v4f*)(base + 16000);
    v4f f1 = *(const v4f*)(base + 16000 + VN_D);
    v4f s2 = *(const v4f*)(base + 32000);
    v4f f2 = *(const v4f*)(base + 32000 + VN_D);
    v4f s3 = *(const v4f*)(base + 48000);
    v4f f3 = *(const v4f*)(base + 48000 + VN_D);
    v4f s4 = *(const v4f*)(base + 64000);
    v4f f4 = *(const v4f*)(base + 64000 + VN_D);
    v4f s5 = *(const v4f*)(base + 80000);
    v4f f5 = *(const v4f*)(base + 80000 + VN_D);
    v4f s6 = *(const v4f*)(base + 96000);
    v4f f6 = *(const v4f*)(base + 96000 + VN_D);
    v4f s7 = *(const v4f*)(base + 112000);
    v4f f7 = *(const v4f*)(base + 112000 + VN_D);

    v4f o0, o1, o2, o3, o4, o5, o6, o7;
#define SEL(o, s, f) \
    o.x = ((int)(23.0f * f.x) == r) ? s.x : 0.0f; \
    o.y = ((int)(23.0f * f.y) == r) ? s.y : 0.0f; \
    o.z = ((int)(23.0f * f.z) == r) ? s.z : 0.0f; \
    o.w = ((int)(23.0f * f.w) == r) ? s.w : 0.0f;
    SEL(o0, s0, f0)
    SEL(o1, s1, f1)
    SEL(o2, s2, f2)
    SEL(o3, s3, f3)
    SEL(o4, s4, f4)
    SEL(o5, s5, f5)
    SEL(o6, s6, f6)
    SEL(o7, s7, f7)
#undef SEL

    // dst chunk stride: 12000 samples * 16 ch = 192000 floats
    float* dst = out + (size_t)b * (VN_N * VN_D) + ((size_t)tid << 2);
    *(v4f*)(dst)           = o0;
    *(v4f*)(dst +  192000) = o1;
    *(v4f*)(dst +  384000) = o2;
    *(v4f*)(dst +  576000) = o3;
    *(v4f*)(dst +  768000) = o4;
    *(v4f*)(dst +  960000) = o5;
    *(v4f*)(dst + 1152000) = o6;
    *(v4f*)(dst + 1344000) = o7;
}

extern "C" void kernel_launch(void* const* d_in, const int* in_sizes, int n_in,
                              void* d_out, int out_size, void* d_ws, size_t ws_size,
                              hipStream_t stream) {
    const float* in = (const float*)d_in[0];
    float* out = (float*)d_out;

    dim3 grid(250, VN_B);   // 250*192 = 48000 threads per b, x8 v4f each
    velvet_gather8<<<grid, 192, 0, stream>>>(in, out);
}

// Round 6
// 205.450 us; speedup vs baseline: 1.0253x; 1.0253x over previous
//
#include <hip/hip_runtime.h>

// VelvetNoise as a pure gather: out[b,n,d] = sgn[b,p,d] * (trunc(23*frac[b,p,d]) == n%24),
// p = n/24. Disjoint scatter windows (jitter in [0,22] < step=24) -> each output
// element is written exactly once: no atomics, no zeroing pass, traffic-optimal
// (196.6 MB coalesced writes + ~16 MB reads; scatter alternative costs more).
//
// R6 = revert to R4 (best measured, 207.2 us): x4 unroll along k (chunks of
// +24000 samples = +1000 pulses; 24000%24==0 so r and the single /24 divide are
// shared), 8 loads issued back-to-back (MLP), 4 coalesced float4 stores.
// R5's x8/192-thread variant regressed (+3.4 us) -> kernel is at its BW floor
// (~40 us vs ~33 us ideal at the 6.7 TB/s the harness fills demonstrate);
// remaining ~170 us of dur_us is fixed harness poison/restore traffic.

#define VN_B  32
#define VN_PS 4000
#define VN_D  16
#define VN_N  96000

typedef float v4f __attribute__((ext_vector_type(4)));

__global__ __launch_bounds__(256) void velvet_gather4(
    const float* __restrict__ in,   // (B, PS, 2*D): [:,:,0:16]=sgn, [:,:,16:32]=frac
    float* __restrict__ out)        // (B, N, D)
{
    const int tid = blockIdx.x * 256 + threadIdx.x;   // [0, 96000) per b
    const int b   = blockIdx.y;

    const int n  = tid >> 2;            // [0, 24000) sample index (k=0)
    const int d0 = (tid & 3) << 2;      // channel group {0,4,8,12}
    const int p  = n / 24;              // magic-mul divide (constant)
    const int r  = n - 24 * p;          // shared by all 4 k-chunks

    const float* base = in + (size_t)b * (VN_PS * 2 * VN_D) + p * (2 * VN_D) + d0;

    // k-chunk input stride: 1000 pulses = 32000 floats. Issue all 8 loads first (MLP).
    v4f s0 = *(const v4f*)(base);
    v4f f0 = *(const v4f*)(base + VN_D);
    v4f s1 = *(const v4f*)(base + 32000);
    v4f f1 = *(const v4f*)(base + 32000 + VN_D);
    v4f s2 = *(const v4f*)(base + 64000);
    v4f f2 = *(const v4f*)(base + 64000 + VN_D);
    v4f s3 = *(const v4f*)(base + 96000);
    v4f f3 = *(const v4f*)(base + 96000 + VN_D);

    v4f o0, o1, o2, o3;
    o0.x = ((int)(23.0f * f0.x) == r) ? s0.x : 0.0f;
    o0.y = ((int)(23.0f * f0.y) == r) ? s0.y : 0.0f;
    o0.z = ((int)(23.0f * f0.z) == r) ? s0.z : 0.0f;
    o0.w = ((int)(23.0f * f0.w) == r) ? s0.w : 0.0f;
    o1.x = ((int)(23.0f * f1.x) == r) ? s1.x : 0.0f;
    o1.y = ((int)(23.0f * f1.y) == r) ? s1.y : 0.0f;
    o1.z = ((int)(23.0f * f1.z) == r) ? s1.z : 0.0f;
    o1.w = ((int)(23.0f * f1.w) == r) ? s1.w : 0.0f;
    o2.x = ((int)(23.0f * f2.x) == r) ? s2.x : 0.0f;
    o2.y = ((int)(23.0f * f2.y) == r) ? s2.y : 0.0f;
    o2.z = ((int)(23.0f * f2.z) == r) ? s2.z : 0.0f;
    o2.w = ((int)(23.0f * f2.w) == r) ? s2.w : 0.0f;
    o3.x = ((int)(23.0f * f3.x) == r) ? s3.x : 0.0f;
    o3.y = ((int)(23.0f * f3.y) == r) ? s3.y : 0.0f;
    o3.z = ((int)(23.0f * f3.z) == r) ? s3.z : 0.0f;
    o3.w = ((int)(23.0f * f3.w) == r) ? s3.w : 0.0f;

    // dst chunk stride: 24000 samples * 16 ch = 384000 floats
    float* dst = out + (size_t)b * (VN_N * VN_D) + ((size_t)tid << 2);
    *(v4f*)(dst)           = o0;
    *(v4f*)(dst +  384000) = o1;
    *(v4f*)(dst +  768000) = o2;
    *(v4f*)(dst + 1152000) = o3;
}

extern "C" void kernel_launch(void* const* d_in, const int* in_sizes, int n_in,
                              void* d_out, int out_size, void* d_ws, size_t ws_size,
                              hipStream_t stream) {
    const float* in = (const float*)d_in[0];
    float* out = (float*)d_out;

    dim3 grid(375, VN_B);   // 375*256 = 96000 threads per b, x4 v4f each
    velvet_gather4<<<grid, 256, 0, stream>>>(in, out);
}